// Round 2
// baseline (1056.635 us; speedup 1.0000x reference)
//
#include <hip/hip_runtime.h>

// ---------- types ----------
typedef __attribute__((ext_vector_type(8))) short short8;   // 8 x bf16
typedef __attribute__((ext_vector_type(4))) short short4v;  // 4 x bf16
typedef __attribute__((ext_vector_type(4))) float float4v;

#define MFMA16(a, b, c) __builtin_amdgcn_mfma_f32_16x16x32_bf16((a), (b), (c), 0, 0, 0)

__device__ __forceinline__ short f2bf(float f) {  // RNE fp32 -> bf16
  unsigned u = __float_as_uint(f);
  u += 0x7fffu + ((u >> 16) & 1u);
  return (short)(u >> 16);
}

// ---------- fused fp32 -> bf16 cast (all 9 tensors, one launch) ----------
struct CastSeg { const float* src; short* dst; int n4; };
struct CastArgs { CastSeg seg[9]; int start[10]; };

__global__ __launch_bounds__(256) void castk(CastArgs a) {
  int blk = blockIdx.x;
  int si = 0;
#pragma unroll
  for (int i = 1; i < 9; i++) si += (blk >= a.start[i]);
  int i = (blk - a.start[si]) * 256 + threadIdx.x;
  if (i >= a.seg[si].n4) return;
  float4v f = ((const float4v*)a.seg[si].src)[i];
  short4v o;
  o[0] = f2bf(f[0]); o[1] = f2bf(f[1]); o[2] = f2bf(f[2]); o[3] = f2bf(f[3]);
  ((short4v*)a.seg[si].dst)[i] = o;
}

// ---------- MFMA GEMM: out[m, ocol+n] = A(M,K) @ W(N,K)^T + bias ----------
// block = 4 waves; wave w: rows [bm + w*16*MT, +16*MT), cols [bn, bn+64)
// ROPE: reference's 768-wide rope on output columns (col index == rope index)
// OUTVT: write V^T global layout [b(4)][col(1536)][s(2048)]
template <int ROPE, int OUTF32, int OUTVT, int MT>
__global__ __launch_bounds__(256) void gemm_mfma(
    const short* __restrict__ A, int lda, const short* __restrict__ W, int ldw,
    const float* __restrict__ bias, float* __restrict__ outf,
    short* __restrict__ outb, int ldo, int ocol, int K,
    const int* __restrict__ pos) {
  int w = threadIdx.x >> 6, lane = threadIdx.x & 63;
  int quad = lane >> 4, l16 = lane & 15;
  int bm = blockIdx.y * 64 * MT, bn = blockIdx.x * 64;

  const short* Ar[MT];
#pragma unroll
  for (int mt = 0; mt < MT; mt++)
    Ar[mt] = A + (size_t)(bm + (w * MT + mt) * 16 + l16) * lda + quad * 8;
  const short* W0 = W + (size_t)(bn + l16) * ldw + quad * 8;

  float4v acc[MT][4];
  float4v z = {0.f, 0.f, 0.f, 0.f};
#pragma unroll
  for (int mt = 0; mt < MT; mt++)
#pragma unroll
    for (int nt = 0; nt < 4; nt++) acc[mt][nt] = z;

#pragma unroll 4
  for (int k = 0; k < K; k += 32) {
    short8 a[MT];
#pragma unroll
    for (int mt = 0; mt < MT; mt++) a[mt] = *(const short8*)(Ar[mt] + k);
#pragma unroll
    for (int nt = 0; nt < 4; nt++) {
      short8 bfrag = *(const short8*)(W0 + (size_t)nt * 16 * ldw + k);
#pragma unroll
      for (int mt = 0; mt < MT; mt++) acc[mt][nt] = MFMA16(a[mt], bfrag, acc[mt][nt]);
    }
  }

#pragma unroll
  for (int mt = 0; mt < MT; mt++) {
#pragma unroll
    for (int nt = 0; nt < 4; nt++) {
      int col = bn + nt * 16 + l16;
      float bv = bias[col];
      float f = 0.f;
      if (ROPE)  // inv_freq = theta^(-(2i)/768), i = col>>1
        f = exp2f((float)(col & ~1) * (-13.287712379549449f / 768.0f));
      int row0 = bm + (w * MT + mt) * 16 + quad * 4;
      if (OUTVT) {
        int bidx = row0 >> 11, s = row0 & 2047;
        short4v ov;
#pragma unroll
        for (int r = 0; r < 4; r++) ov[r] = f2bf(acc[mt][nt][r] + bv);
        *(short4v*)(outb + ((size_t)(bidx * 1536 + col)) * 2048 + s) = ov;
      } else {
#pragma unroll
        for (int r = 0; r < 4; r++) {
          int row = row0 + r;
          float v = acc[mt][nt][r] + bv;
          float res;
          if (ROPE) {
            float pv = __shfl_xor(v, 1, 64);  // partner column (col^1)
            float ang = (float)pos[row & 2047] * f;
            float sn, cs;
            sincosf(ang, &sn, &cs);
            res = (col & 1) ? (pv * sn + v * cs) : (v * cs - pv * sn);
          } else {
            res = v;
          }
          if (OUTF32)
            outf[(size_t)row * ldo + ocol + col] = res;
          else
            outb[(size_t)row * ldo + ocol + col] = f2bf(res);
        }
      }
    }
  }
}

// ---------- causal flash attention, barrier-free ----------
// One wave owns a 16-row q-tile; K read direct from global (row-major),
// V read direct from global V^T [b][h*128+d][s]; only P round-trips per-wave LDS.
template <bool MASK>
__device__ __forceinline__ void attn_step(
    int kt, int qt, int quad, int l16, const short* __restrict__ kb,
    const short* __restrict__ vb, short* __restrict__ plw, const short8* qf,
    float4v* oacc, float* m_i, float* l_i) {
  const float C = 0.12751743f;  // (1/sqrt(128)) * log2(e)
  float4v z = {0.f, 0.f, 0.f, 0.f};
  float4v s0 = z, s1 = z;
  const short* k0 = kb + (size_t)kt * 1536;
#pragma unroll
  for (int c = 0; c < 4; c++) {
    short8 b0 = *(const short8*)(k0 + c * 32);
    short8 b1 = *(const short8*)(k0 + 16 * 1536 + c * 32);
    s0 = MFMA16(qf[c], b0, s0);
    s1 = MFMA16(qf[c], b1, s1);
  }
#pragma unroll
  for (int r = 0; r < 4; r++) {
    float a0 = s0[r], a1 = s1[r];
    if (MASK) {
      int qr = qt + quad * 4 + r;
      if (kt + l16 > qr) a0 = -3e38f;
      if (kt + 16 + l16 > qr) a1 = -3e38f;
    }
    float mm = fmaxf(a0, a1);
    mm = fmaxf(mm, __shfl_xor(mm, 1, 64));
    mm = fmaxf(mm, __shfl_xor(mm, 2, 64));
    mm = fmaxf(mm, __shfl_xor(mm, 4, 64));
    mm = fmaxf(mm, __shfl_xor(mm, 8, 64));
    float mnew = fmaxf(m_i[r], mm);
    float alpha = exp2f((m_i[r] - mnew) * C);
    float p0 = exp2f((a0 - mnew) * C);
    float p1 = exp2f((a1 - mnew) * C);
    float ps = p0 + p1;
    ps += __shfl_xor(ps, 1, 64);
    ps += __shfl_xor(ps, 2, 64);
    ps += __shfl_xor(ps, 4, 64);
    ps += __shfl_xor(ps, 8, 64);
    l_i[r] = l_i[r] * alpha + ps;
    m_i[r] = mnew;
#pragma unroll
    for (int n = 0; n < 8; n++) oacc[n][r] *= alpha;
    plw[(quad * 4 + r) * 40 + l16] = f2bf(p0);
    plw[(quad * 4 + r) * 40 + 16 + l16] = f2bf(p1);
  }
  short8 pf = *(const short8*)(plw + l16 * 40 + quad * 8);
#pragma unroll
  for (int nt = 0; nt < 8; nt++) {
    short8 bv = *(const short8*)(vb + (size_t)nt * 16 * 2048 + kt);
    oacc[nt] = MFMA16(pf, bv, oacc[nt]);
  }
}

__global__ __launch_bounds__(256) void mla_attn(const short* __restrict__ Q,
                                                const short* __restrict__ K,
                                                const short* __restrict__ Vt,
                                                short* __restrict__ O) {
  const int ld = 1536, SEQ = 2048;
  int tid = threadIdx.x, w = tid >> 6, lane = tid & 63;
  int quad = lane >> 4, l16 = lane & 15;
  int qt = (blockIdx.x * 4 + w) * 16;  // adjacent waves -> adjacent q-tiles (L1 K reuse)
  int h = blockIdx.y, b = blockIdx.z;

  __shared__ short Pl[4][16 * 40];
  short* plw = Pl[w];

  const short* Qb = Q + ((size_t)b * SEQ) * ld + h * 128;
  const short* kb = K + ((size_t)b * SEQ) * ld + h * 128 + (size_t)l16 * ld + quad * 8;
  const short* vb = Vt + ((size_t)(b * 12 + h) * 128 + l16) * SEQ + quad * 8;

  short8 qf[4];
#pragma unroll
  for (int c = 0; c < 4; c++)
    qf[c] = *(const short8*)(Qb + (size_t)(qt + l16) * ld + c * 32 + quad * 8);

  float4v oacc[8];
  float4v z = {0.f, 0.f, 0.f, 0.f};
#pragma unroll
  for (int n = 0; n < 8; n++) oacc[n] = z;
  float m_i[4] = {-1e30f, -1e30f, -1e30f, -1e30f};
  float l_i[4] = {0.f, 0.f, 0.f, 0.f};

  int nfull = (qt + 1) >> 5;  // unmasked 32-key iterations
  int kt = 0;
  for (; kt < nfull * 32; kt += 32)
    attn_step<false>(kt, qt, quad, l16, kb, vb, plw, qf, oacc, m_i, l_i);
  attn_step<true>(kt, qt, quad, l16, kb, vb, plw, qf, oacc, m_i, l_i);

  float inv[4];
#pragma unroll
  for (int r = 0; r < 4; r++) inv[r] = 1.0f / l_i[r];
  short* Ob = O + ((size_t)b * SEQ + qt) * ld + h * 128;
#pragma unroll
  for (int nt = 0; nt < 8; nt++) {
#pragma unroll
    for (int r = 0; r < 4; r++)
      Ob[(size_t)(quad * 4 + r) * ld + nt * 16 + l16] = f2bf(oacc[nt][r] * inv[r]);
  }
}

// ---------- launcher ----------
extern "C" void kernel_launch(void* const* d_in, const int* in_sizes, int n_in,
                              void* d_out, int out_size, void* d_ws, size_t ws_size,
                              hipStream_t stream) {
  const int S = 2048, DM = 768, DL = 128, HD = 1536;
  const int M = 4 * S;  // 8192

  const float* x = (const float*)d_in[0];
  const int* pos = (const int*)d_in[1];
  const float* W_dkv = (const float*)d_in[2];
  const float* b_dkv = (const float*)d_in[3];
  const float* W_dq = (const float*)d_in[4];
  const float* b_dq = (const float*)d_in[5];
  const float* W_uk_nope = (const float*)d_in[6];
  const float* b_uk_nope = (const float*)d_in[7];
  const float* W_uv = (const float*)d_in[8];
  const float* b_uv = (const float*)d_in[9];
  const float* W_uq_nope = (const float*)d_in[10];
  const float* b_uq_nope = (const float*)d_in[11];
  const float* W_uq_rope = (const float*)d_in[12];
  const float* b_uq_rope = (const float*)d_in[13];
  const float* W_uk_rope = (const float*)d_in[14];
  const float* b_uk_rope = (const float*)d_in[15];
  const float* W_o = (const float*)d_in[16];
  const float* b_o = (const float*)d_in[17];

  char* p = (char*)d_ws;
  size_t off = 0;
  auto take = [&](size_t nelem) -> short* {
    short* r = (short*)(p + off);
    off += (nelem * 2 + 255) & ~(size_t)255;
    return r;
  };
  short* xb = take((size_t)M * DM);
  short* Wdkv = take(DL * DM);
  short* Wdq = take(DL * DM);
  short* Wuknope = take(768 * DL);
  short* Wuv = take(1536 * DL);
  short* Wuqnope = take(768 * DL);
  short* Wuqrope = take(768 * DL);
  short* Wukrope = take(768 * DM);
  short* Wo = take(768 * 1536);
  short* Cq = take((size_t)M * DL);
  short* Ckv = take((size_t)M * DL);
  short* Qm = take((size_t)M * HD);
  short* Km = take((size_t)M * HD);
  short* Vtm = take((size_t)M * HD);  // V^T: [b][h*128+d][s]
  short* Om = take((size_t)M * HD);
  if (off > ws_size) return;

  // one fused cast launch
  CastArgs ca;
  const float* srcs[9] = {x, W_dkv, W_dq, W_uk_nope, W_uv, W_uq_nope, W_uq_rope, W_uk_rope, W_o};
  short* dsts[9] = {xb, Wdkv, Wdq, Wuknope, Wuv, Wuqnope, Wuqrope, Wukrope, Wo};
  int ns[9] = {M * DM, DL * DM, DL * DM, 768 * DL, 1536 * DL, 768 * DL, 768 * DL, 768 * DM, 768 * 1536};
  ca.start[0] = 0;
  for (int i = 0; i < 9; i++) {
    ca.seg[i].src = srcs[i];
    ca.seg[i].dst = dsts[i];
    ca.seg[i].n4 = ns[i] / 4;
    ca.start[i + 1] = ca.start[i] + (ca.seg[i].n4 + 255) / 256;
  }
  castk<<<dim3(ca.start[9]), dim3(256), 0, stream>>>(ca);

  // C_q, C_kv (N=128: 64-row blocks to keep grid >= 256)
  gemm_mfma<0, 0, 0, 1><<<dim3(2, M / 64), dim3(256), 0, stream>>>(
      xb, DM, Wdq, DM, b_dq, nullptr, Cq, DL, 0, DM, pos);
  gemm_mfma<0, 0, 0, 1><<<dim3(2, M / 64), dim3(256), 0, stream>>>(
      xb, DM, Wdkv, DM, b_dkv, nullptr, Ckv, DL, 0, DM, pos);
  // Q = [q_nope | rope(q_rope)]
  gemm_mfma<0, 0, 0, 2><<<dim3(12, M / 128), dim3(256), 0, stream>>>(
      Cq, DL, Wuqnope, DL, b_uq_nope, nullptr, Qm, HD, 0, DL, pos);
  gemm_mfma<1, 0, 0, 2><<<dim3(12, M / 128), dim3(256), 0, stream>>>(
      Cq, DL, Wuqrope, DL, b_uq_rope, nullptr, Qm, HD, 768, DL, pos);
  // K = [k_nope | rope(k_rope)]
  gemm_mfma<0, 0, 0, 2><<<dim3(12, M / 128), dim3(256), 0, stream>>>(
      Ckv, DL, Wuknope, DL, b_uk_nope, nullptr, Km, HD, 0, DL, pos);
  gemm_mfma<1, 0, 0, 2><<<dim3(12, M / 128), dim3(256), 0, stream>>>(
      xb, DM, Wukrope, DM, b_uk_rope, nullptr, Km, HD, 768, DM, pos);
  // V -> V^T
  gemm_mfma<0, 0, 1, 2><<<dim3(24, M / 128), dim3(256), 0, stream>>>(
      Ckv, DL, Wuv, DL, b_uv, nullptr, Vtm, 0, 0, DL, pos);
  // attention
  mla_attn<<<dim3(32, 12, 4), dim3(256), 0, stream>>>(Qm, Km, Vtm, Om);
  // out = O @ W_o^T + b_o  (fp32)
  gemm_mfma<0, 1, 0, 2><<<dim3(12, M / 128), dim3(256), 0, stream>>>(
      Om, HD, Wo, HD, b_o, (float*)d_out, nullptr, 768, 0, HD, pos);
}

// Round 3
// 677.507 us; speedup vs baseline: 1.5596x; 1.5596x over previous
//
#include <hip/hip_runtime.h>

// ---------- types ----------
typedef __attribute__((ext_vector_type(8))) short short8;   // 8 x bf16
typedef __attribute__((ext_vector_type(4))) short short4v;  // 4 x bf16
typedef __attribute__((ext_vector_type(4))) float float4v;

#define MFMA16(a, b, c) __builtin_amdgcn_mfma_f32_16x16x32_bf16((a), (b), (c), 0, 0, 0)

__device__ __forceinline__ short f2bf(float f) {  // RNE fp32 -> bf16
  unsigned u = __float_as_uint(f);
  u += 0x7fffu + ((u >> 16) & 1u);
  return (short)(u >> 16);
}

// ---------- fused fp32 -> bf16 cast (all 9 tensors, one launch) ----------
struct CastSeg { const float* src; short* dst; int n4; };
struct CastArgs { CastSeg seg[9]; int start[10]; };

__global__ __launch_bounds__(256) void castk(CastArgs a) {
  int blk = blockIdx.x;
  int si = 0;
#pragma unroll
  for (int i = 1; i < 9; i++) si += (blk >= a.start[i]);
  int i = (blk - a.start[si]) * 256 + threadIdx.x;
  if (i >= a.seg[si].n4) return;
  float4v f = ((const float4v*)a.seg[si].src)[i];
  short4v o;
  o[0] = f2bf(f[0]); o[1] = f2bf(f[1]); o[2] = f2bf(f[2]); o[3] = f2bf(f[3]);
  ((short4v*)a.seg[si].dst)[i] = o;
}

// ---------- MFMA GEMM: out[m, ocol+n] = A(M,K) @ W(N,K)^T + bias ----------
template <int ROPE, int OUTF32, int OUTVT, int MT>
__global__ __launch_bounds__(256) void gemm_mfma(
    const short* __restrict__ A, int lda, const short* __restrict__ W, int ldw,
    const float* __restrict__ bias, float* __restrict__ outf,
    short* __restrict__ outb, int ldo, int ocol, int K,
    const int* __restrict__ pos) {
  int w = threadIdx.x >> 6, lane = threadIdx.x & 63;
  int quad = lane >> 4, l16 = lane & 15;
  int bm = blockIdx.y * 64 * MT, bn = blockIdx.x * 64;

  const short* Ar[MT];
#pragma unroll
  for (int mt = 0; mt < MT; mt++)
    Ar[mt] = A + (size_t)(bm + (w * MT + mt) * 16 + l16) * lda + quad * 8;
  const short* W0 = W + (size_t)(bn + l16) * ldw + quad * 8;

  float4v acc[MT][4];
  float4v z = {0.f, 0.f, 0.f, 0.f};
#pragma unroll
  for (int mt = 0; mt < MT; mt++)
#pragma unroll
    for (int nt = 0; nt < 4; nt++) acc[mt][nt] = z;

#pragma unroll 4
  for (int k = 0; k < K; k += 32) {
    short8 a[MT];
#pragma unroll
    for (int mt = 0; mt < MT; mt++) a[mt] = *(const short8*)(Ar[mt] + k);
#pragma unroll
    for (int nt = 0; nt < 4; nt++) {
      short8 bfrag = *(const short8*)(W0 + (size_t)nt * 16 * ldw + k);
#pragma unroll
      for (int mt = 0; mt < MT; mt++) acc[mt][nt] = MFMA16(a[mt], bfrag, acc[mt][nt]);
    }
  }

#pragma unroll
  for (int mt = 0; mt < MT; mt++) {
#pragma unroll
    for (int nt = 0; nt < 4; nt++) {
      int col = bn + nt * 16 + l16;
      float bv = bias[col];
      float f = 0.f;
      if (ROPE)  // inv_freq = theta^(-(2i)/768), i = col>>1
        f = exp2f((float)(col & ~1) * (-13.287712379549449f / 768.0f));
      int row0 = bm + (w * MT + mt) * 16 + quad * 4;
      if (OUTVT) {
        int bidx = row0 >> 11, s = row0 & 2047;
        short4v ov;
#pragma unroll
        for (int r = 0; r < 4; r++) ov[r] = f2bf(acc[mt][nt][r] + bv);
        *(short4v*)(outb + ((size_t)(bidx * 1536 + col)) * 2048 + s) = ov;
      } else {
#pragma unroll
        for (int r = 0; r < 4; r++) {
          int row = row0 + r;
          float v = acc[mt][nt][r] + bv;
          float res;
          if (ROPE) {
            float pv = __shfl_xor(v, 1, 64);  // partner column (col^1)
            float ang = (float)pos[row & 2047] * f;
            float sn, cs;
            sincosf(ang, &sn, &cs);
            res = (col & 1) ? (pv * sn + v * cs) : (v * cs - pv * sn);
          } else {
            res = v;
          }
          if (OUTF32)
            outf[(size_t)row * ldo + ocol + col] = res;
          else
            outb[(size_t)row * ldo + ocol + col] = f2bf(res);
        }
      }
    }
  }
}

// ---------- causal flash attention: S^T = K*Q^T trick, LDS-staged, pipelined ----------
// grid (16, 12, 4); block 256 (4 waves). Wave w: 32 q-rows. Block: 128 q-rows.
// K-tile 64 keys (row-major, stride 136 shorts), V^T-tile 128d x 64keys (stride 72),
// P per-wave 32q x 64keys (stride 68). All strides chosen for uniform bank spread.
__global__ __launch_bounds__(256) void mla_attn(const short* __restrict__ Q,
                                                const short* __restrict__ K,
                                                const short* __restrict__ Vt,
                                                short* __restrict__ O) {
  const int ld = 1536, SEQ = 2048;
  int tid = threadIdx.x, w = tid >> 6, lane = tid & 63;
  int quad = lane >> 4, l16 = lane & 15;
  int qt = (gridDim.x - 1 - blockIdx.x) * 128;  // longest blocks dispatch first
  int hh = blockIdx.y, b = blockIdx.z;
  int qw = qt + w * 32;

  __shared__ short Kt[64 * 136];
  __shared__ short Vl[128 * 72];
  __shared__ short Pt[4][32 * 68];
  short* pw = Pt[w];

  // Q fragments (held in regs whole kernel): qf[nf][ks]
  short8 qf[2][4];
  {
    const short* Qg = Q + (size_t)(b * SEQ + qw + l16) * ld + hh * 128 + quad * 8;
#pragma unroll
    for (int nf = 0; nf < 2; nf++)
#pragma unroll
      for (int ks = 0; ks < 4; ks++)
        qf[nf][ks] = *(const short8*)(Qg + (size_t)nf * 16 * ld + ks * 32);
  }

  float4v z = {0.f, 0.f, 0.f, 0.f};
  float4v oacc[2][8];
#pragma unroll
  for (int mq = 0; mq < 2; mq++)
#pragma unroll
    for (int df = 0; df < 8; df++) oacc[mq][df] = z;
  float m_i[2] = {-1e30f, -1e30f}, l_i[2] = {0.f, 0.f};
  const float C = 0.12751743f;  // (1/sqrt(128)) * log2(e)

  // staging assignment: K 64 rows x 128 shorts; V^T 128 rows x 64 shorts
  int krow = tid >> 2, kc = (tid & 3) * 32;
  int vrow = tid >> 1, vc = (tid & 1) * 32;
  const short* kgp = K + (size_t)(b * SEQ + krow) * ld + hh * 128 + kc;
  const short* vgp = Vt + ((size_t)(b * 12 + hh) * 128 + vrow) * SEQ + vc;

  short8 kreg[4], vreg[4];
#pragma unroll
  for (int i = 0; i < 4; i++) kreg[i] = *(const short8*)(kgp + i * 8);
#pragma unroll
  for (int i = 0; i < 4; i++) vreg[i] = *(const short8*)(vgp + i * 8);

  int ktend = qt + 64;
  for (int kt = 0; kt <= ktend; kt += 64) {
    __syncthreads();  // previous tile's LDS reads done
#pragma unroll
    for (int i = 0; i < 4; i++) *(short8*)(&Kt[krow * 136 + kc + i * 8]) = kreg[i];
#pragma unroll
    for (int i = 0; i < 4; i++) *(short8*)(&Vl[vrow * 72 + vc + i * 8]) = vreg[i];
    __syncthreads();  // staging visible
    if (kt < ktend) {  // prefetch next tile (overlaps with compute below)
#pragma unroll
      for (int i = 0; i < 4; i++)
        kreg[i] = *(const short8*)(kgp + (size_t)(kt + 64) * ld + i * 8);
#pragma unroll
      for (int i = 0; i < 4; i++)
        vreg[i] = *(const short8*)(vgp + (kt + 64) + i * 8);
    }
    if (kt <= qw + 31) {  // wave-uniform: skip fully-masked tiles
      // ---- S^T = K * Q^T : A=K frag, B=Q frag; C: col=q(l16), row=key(quad*4+r)
      float4v sf[4][2];
#pragma unroll
      for (int mf = 0; mf < 4; mf++)
#pragma unroll
        for (int nf = 0; nf < 2; nf++) sf[mf][nf] = z;
#pragma unroll
      for (int ks = 0; ks < 4; ks++) {
#pragma unroll
        for (int mf = 0; mf < 4; mf++) {
          short8 a = *(const short8*)(&Kt[(mf * 16 + l16) * 136 + ks * 32 + quad * 8]);
#pragma unroll
          for (int nf = 0; nf < 2; nf++)
            sf[mf][nf] = MFMA16(a, qf[nf][ks], sf[mf][nf]);
        }
      }
      // ---- causal mask (only near diagonal) ----
      if (kt + 63 > qw) {
#pragma unroll
        for (int mf = 0; mf < 4; mf++) {
          int key = kt + mf * 16 + quad * 4;
#pragma unroll
          for (int nf = 0; nf < 2; nf++) {
            int q = qw + nf * 16 + l16;
#pragma unroll
            for (int r = 0; r < 4; r++)
              if (key + r > q) sf[mf][nf][r] = -3e38f;
          }
        }
      }
      // ---- online softmax: per-lane q-column, 2 shuffles per reduction ----
      float alpha[2];
#pragma unroll
      for (int nf = 0; nf < 2; nf++) {
        float mx = sf[0][nf][0];
#pragma unroll
        for (int mf = 0; mf < 4; mf++)
#pragma unroll
          for (int r = 0; r < 4; r++) mx = fmaxf(mx, sf[mf][nf][r]);
        mx = fmaxf(mx, __shfl_xor(mx, 16, 64));
        mx = fmaxf(mx, __shfl_xor(mx, 32, 64));
        float mnew = fmaxf(m_i[nf], mx);
        alpha[nf] = exp2f((m_i[nf] - mnew) * C);
        float ps = 0.f;
#pragma unroll
        for (int mf = 0; mf < 4; mf++)
#pragma unroll
          for (int r = 0; r < 4; r++) {
            float e = exp2f((sf[mf][nf][r] - mnew) * C);
            sf[mf][nf][r] = e;
            ps += e;
          }
        ps += __shfl_xor(ps, 16, 64);
        ps += __shfl_xor(ps, 32, 64);
        l_i[nf] = l_i[nf] * alpha[nf] + ps;
        m_i[nf] = mnew;
      }
      // ---- P -> LDS (packed b64 writes: 4 consecutive keys per reg group) ----
#pragma unroll
      for (int nf = 0; nf < 2; nf++)
#pragma unroll
        for (int mf = 0; mf < 4; mf++) {
          short4v p4;
#pragma unroll
          for (int r = 0; r < 4; r++) p4[r] = f2bf(sf[mf][nf][r]);
          *(short4v*)(&pw[(nf * 16 + l16) * 68 + mf * 16 + quad * 4]) = p4;
        }
      // ---- rescale O by alpha (broadcast per O-row via shfl) ----
#pragma unroll
      for (int mq = 0; mq < 2; mq++) {
        float av[4];
#pragma unroll
        for (int r = 0; r < 4; r++) av[r] = __shfl(alpha[mq], quad * 4 + r, 64);
#pragma unroll
        for (int df = 0; df < 8; df++)
#pragma unroll
          for (int r = 0; r < 4; r++) oacc[mq][df][r] *= av[r];
      }
      // ---- O += P * V : A=P frag (b128 from pw), B=V frag (b128 from Vl) ----
#pragma unroll
      for (int t = 0; t < 2; t++) {
        short8 pf[2];
#pragma unroll
        for (int mq = 0; mq < 2; mq++)
          pf[mq] = *(const short8*)(&pw[(mq * 16 + l16) * 68 + t * 32 + quad * 8]);
#pragma unroll
        for (int df = 0; df < 8; df++) {
          short8 vf = *(const short8*)(&Vl[(df * 16 + l16) * 72 + t * 32 + quad * 8]);
#pragma unroll
          for (int mq = 0; mq < 2; mq++)
            oacc[mq][df] = MFMA16(pf[mq], vf, oacc[mq][df]);
        }
      }
    }
  }

  // ---- epilogue ----
  short* Og = O + (size_t)(b * SEQ + qw) * ld + hh * 128;
#pragma unroll
  for (int mq = 0; mq < 2; mq++) {
    float linv = 1.0f / l_i[mq];
    float lb[4];
#pragma unroll
    for (int r = 0; r < 4; r++) lb[r] = __shfl(linv, quad * 4 + r, 64);
#pragma unroll
    for (int df = 0; df < 8; df++)
#pragma unroll
      for (int r = 0; r < 4; r++)
        Og[(size_t)(mq * 16 + quad * 4 + r) * ld + df * 16 + l16] =
            f2bf(oacc[mq][df][r] * lb[r]);
  }
}

// ---------- launcher ----------
extern "C" void kernel_launch(void* const* d_in, const int* in_sizes, int n_in,
                              void* d_out, int out_size, void* d_ws, size_t ws_size,
                              hipStream_t stream) {
  const int S = 2048, DM = 768, DL = 128, HD = 1536;
  const int M = 4 * S;  // 8192

  const float* x = (const float*)d_in[0];
  const int* pos = (const int*)d_in[1];
  const float* W_dkv = (const float*)d_in[2];
  const float* b_dkv = (const float*)d_in[3];
  const float* W_dq = (const float*)d_in[4];
  const float* b_dq = (const float*)d_in[5];
  const float* W_uk_nope = (const float*)d_in[6];
  const float* b_uk_nope = (const float*)d_in[7];
  const float* W_uv = (const float*)d_in[8];
  const float* b_uv = (const float*)d_in[9];
  const float* W_uq_nope = (const float*)d_in[10];
  const float* b_uq_nope = (const float*)d_in[11];
  const float* W_uq_rope = (const float*)d_in[12];
  const float* b_uq_rope = (const float*)d_in[13];
  const float* W_uk_rope = (const float*)d_in[14];
  const float* b_uk_rope = (const float*)d_in[15];
  const float* W_o = (const float*)d_in[16];
  const float* b_o = (const float*)d_in[17];

  char* p = (char*)d_ws;
  size_t off = 0;
  auto take = [&](size_t nelem) -> short* {
    short* r = (short*)(p + off);
    off += (nelem * 2 + 255) & ~(size_t)255;
    return r;
  };
  short* xb = take((size_t)M * DM);
  short* Wdkv = take(DL * DM);
  short* Wdq = take(DL * DM);
  short* Wuknope = take(768 * DL);
  short* Wuv = take(1536 * DL);
  short* Wuqnope = take(768 * DL);
  short* Wuqrope = take(768 * DL);
  short* Wukrope = take(768 * DM);
  short* Wo = take(768 * 1536);
  short* Cq = take((size_t)M * DL);
  short* Ckv = take((size_t)M * DL);
  short* Qm = take((size_t)M * HD);
  short* Km = take((size_t)M * HD);
  short* Vtm = take((size_t)M * HD);  // V^T: [b][h*128+d][s]
  short* Om = take((size_t)M * HD);
  if (off > ws_size) return;

  // one fused cast launch
  CastArgs ca;
  const float* srcs[9] = {x, W_dkv, W_dq, W_uk_nope, W_uv, W_uq_nope, W_uq_rope, W_uk_rope, W_o};
  short* dsts[9] = {xb, Wdkv, Wdq, Wuknope, Wuv, Wuqnope, Wuqrope, Wukrope, Wo};
  int ns[9] = {M * DM, DL * DM, DL * DM, 768 * DL, 1536 * DL, 768 * DL, 768 * DL, 768 * DM, 768 * 1536};
  ca.start[0] = 0;
  for (int i = 0; i < 9; i++) {
    ca.seg[i].src = srcs[i];
    ca.seg[i].dst = dsts[i];
    ca.seg[i].n4 = ns[i] / 4;
    ca.start[i + 1] = ca.start[i] + (ca.seg[i].n4 + 255) / 256;
  }
  castk<<<dim3(ca.start[9]), dim3(256), 0, stream>>>(ca);

  // C_q, C_kv
  gemm_mfma<0, 0, 0, 1><<<dim3(2, M / 64), dim3(256), 0, stream>>>(
      xb, DM, Wdq, DM, b_dq, nullptr, Cq, DL, 0, DM, pos);
  gemm_mfma<0, 0, 0, 1><<<dim3(2, M / 64), dim3(256), 0, stream>>>(
      xb, DM, Wdkv, DM, b_dkv, nullptr, Ckv, DL, 0, DM, pos);
  // Q = [q_nope | rope(q_rope)]
  gemm_mfma<0, 0, 0, 2><<<dim3(12, M / 128), dim3(256), 0, stream>>>(
      Cq, DL, Wuqnope, DL, b_uq_nope, nullptr, Qm, HD, 0, DL, pos);
  gemm_mfma<1, 0, 0, 2><<<dim3(12, M / 128), dim3(256), 0, stream>>>(
      Cq, DL, Wuqrope, DL, b_uq_rope, nullptr, Qm, HD, 768, DL, pos);
  // K = [k_nope | rope(k_rope)]
  gemm_mfma<0, 0, 0, 2><<<dim3(12, M / 128), dim3(256), 0, stream>>>(
      Ckv, DL, Wuknope, DL, b_uk_nope, nullptr, Km, HD, 0, DL, pos);
  gemm_mfma<1, 0, 0, 2><<<dim3(12, M / 128), dim3(256), 0, stream>>>(
      xb, DM, Wukrope, DM, b_uk_rope, nullptr, Km, HD, 768, DM, pos);
  // V -> V^T
  gemm_mfma<0, 0, 1, 2><<<dim3(24, M / 128), dim3(256), 0, stream>>>(
      Ckv, DL, Wuv, DL, b_uv, nullptr, Vtm, 0, 0, DL, pos);
  // attention
  mla_attn<<<dim3(16, 12, 4), dim3(256), 0, stream>>>(Qm, Km, Vtm, Om);
  // out = O @ W_o^T + b_o  (fp32)
  gemm_mfma<0, 1, 0, 2><<<dim3(12, M / 128), dim3(256), 0, stream>>>(
      Om, HD, Wo, HD, b_o, (float*)d_out, nullptr, 768, 0, HD, pos);
}